// Round 2
// baseline (199.766 us; speedup 1.0000x reference)
//
#include <hip/hip_runtime.h>
#include <math.h>

#define NB 32
#define LL 512
#define HH 1024
#define H2 512
#define DA 64

typedef unsigned int u32;
typedef unsigned short u16;
typedef __bf16 bf16x8 __attribute__((ext_vector_type(8)));
typedef float f32x4 __attribute__((ext_vector_type(4)));

__device__ __forceinline__ u16 f2bu(float f) {          // fp32 -> bf16 bits, RNE
    u32 u = __builtin_bit_cast(u32, f);
    u = (u + 0x7fff + ((u >> 16) & 1)) >> 16;
    return (u16)u;
}

__device__ __forceinline__ float b2f(u16 u) {           // bf16 bits -> fp32
    u32 v = (u32)u << 16;
    return __builtin_bit_cast(float, v);
}

__device__ __forceinline__ void async_cp16(const void* g, void* l) {
    __builtin_amdgcn_global_load_lds(
        (const __attribute__((address_space(1))) u32*)g,
        (__attribute__((address_space(3))) u32*)l, 16, 0, 0);
}

// ========== prep: bf16 weights (blocks 0..1535) + LN stats (blocks 1536..5631) ==========
__global__ void prep_kernel(const float* __restrict__ wv,
                            const float* __restrict__ kqvw,
                            const float* __restrict__ projw,
                            const float* __restrict__ x,
                            u16* __restrict__ wt, u16* __restrict__ kqvwT,
                            u16* __restrict__ projwT, float2* __restrict__ stats) {
    int blk = blockIdx.x, t = threadIdx.x;
    if (blk < 1536) {
        int e = blk * 256 + t;
        if (e < 262144) {
            int m = e >> 9, l = e & 511;
            wt[e] = f2bu(wv[511 + m - l]);
        } else if (e < 262144 + 98304) {
            int i = e - 262144;
            int n = i >> 9, k = i & 511;
            kqvwT[i] = f2bu(kqvw[(size_t)k * 192 + n]);
        } else {
            int i = e - 360448;
            int c = i >> 6, d = i & 63;
            projwT[i] = f2bu(projw[(size_t)d * 512 + c]);
        }
    } else {
        // LN stats: one wave per row, fully coalesced
        int row = (blk - 1536) * 4 + (t >> 6);
        int lane = t & 63;
        const float* xr = x + (size_t)row * HH + H2;
        float4 a = *(const float4*)(xr + lane * 4);
        float4 c = *(const float4*)(xr + 256 + lane * 4);
        float s1 = a.x + a.y + a.z + a.w + c.x + c.y + c.z + c.w;
        float s2 = a.x*a.x + a.y*a.y + a.z*a.z + a.w*a.w
                 + c.x*c.x + c.y*c.y + c.z*c.z + c.w*c.w;
        s1 += __shfl_xor(s1, 1);  s2 += __shfl_xor(s2, 1);
        s1 += __shfl_xor(s1, 2);  s2 += __shfl_xor(s2, 2);
        s1 += __shfl_xor(s1, 4);  s2 += __shfl_xor(s2, 4);
        s1 += __shfl_xor(s1, 8);  s2 += __shfl_xor(s2, 8);
        s1 += __shfl_xor(s1, 16); s2 += __shfl_xor(s2, 16);
        s1 += __shfl_xor(s1, 32); s2 += __shfl_xor(s2, 32);
        if (lane == 0) {
            float mu = s1 * (1.0f / H2);
            float rstd = rsqrtf(s2 * (1.0f / H2) - mu * mu + 1e-5f);
            stats[row] = make_float2(mu, rstd);
        }
    }
}

// ========== front: affine+transpose (stats precomputed) + barrier-free kqv GEMM ==========
// 1024 blocks of 16 rows; LDS = one 18.5 KB transpose tile -> 4 blocks/CU.
// GEMM reads A from x (L2/L3-hot re-read, in-reg bf16 convert) and B fragments
// straight from kqvwT (L2-resident, shared by all blocks): no LDS, no barriers.
__global__ __launch_bounds__(256, 4)
void front_kernel(const float* __restrict__ x,
                  const float* __restrict__ gamma, const float* __restrict__ beta,
                  const float2* __restrict__ stats,
                  const u16* __restrict__ kqvwT, const float* __restrict__ kqvb,
                  u16* __restrict__ vnT,
                  u16* __restrict__ qb, u16* __restrict__ kb, u16* __restrict__ vT) {
    __shared__ u16 T[512 * 18];                 // T[c*18+r] = bf16(vn[l0+r][c]), affined
    int blk = blockIdx.x, t = threadIdx.x;
    int b = blk >> 5, l0 = (blk & 31) * 16;
    int lane = t & 63, wid = t >> 6;
    int l15 = lane & 15, q16 = lane >> 4, q8 = q16 * 8;

    // ---- phase A: read x coalesced (16 lanes/row), affine, write transposed ----
    {
        int r = t >> 4;                         // 0..15: local row
        int c00 = (t & 15) * 4;                 // col chunk base
        float2 st = stats[(size_t)(b * LL + l0 + r)];
        const float* xr = x + ((size_t)(b * LL + l0 + r)) * HH + H2;
#pragma unroll
        for (int i = 0; i < 8; ++i) {
            int c = c00 + i * 64;
            float4 v = *(const float4*)(xr + c);
            float4 g = *(const float4*)(gamma + c);
            float4 be = *(const float4*)(beta + c);
            T[(c + 0) * 18 + r] = f2bu((v.x - st.x) * st.y * g.x + be.x);
            T[(c + 1) * 18 + r] = f2bu((v.y - st.x) * st.y * g.y + be.y);
            T[(c + 2) * 18 + r] = f2bu((v.z - st.x) * st.y * g.z + be.z);
            T[(c + 3) * 18 + r] = f2bu((v.w - st.x) * st.y * g.w + be.w);
        }
    }
    __syncthreads();

    // ---- phase B: copy T -> vnT (coalesced 32B runs, conflict-free reads) ----
    {
        int cb = t >> 1, h = t & 1;
#pragma unroll
        for (int pass = 0; pass < 4; ++pass) {
            int c = pass * 128 + cb;
            const u16* Tp = T + c * 18 + h * 8;
            ushort4 t0 = ((const ushort4*)Tp)[0];
            ushort4 t1 = ((const ushort4*)(Tp + 4))[0];
            u16* dst = vnT + ((size_t)(b * H2 + c)) * LL + l0 + h * 8;
            ((ushort4*)dst)[0] = t0;
            ((ushort4*)dst)[1] = t1;
        }
    }

    // ---- phase C: kqv GEMM, M=16, N=192 (48/wave), K=512 -- no LDS, no barriers ----
    int wn = wid * 48;
    size_t arow = ((size_t)(b * LL + l0 + l15)) * HH + H2;
    f32x4 acc[3] = {};
#pragma unroll 4
    for (int it = 0; it < 16; ++it) {
        float4 v0 = *(const float4*)(x + arow + it * 32 + q8);
        float4 v1 = *(const float4*)(x + arow + it * 32 + q8 + 4);
        bf16x8 a;
        a[0] = __builtin_bit_cast(__bf16, f2bu(v0.x));
        a[1] = __builtin_bit_cast(__bf16, f2bu(v0.y));
        a[2] = __builtin_bit_cast(__bf16, f2bu(v0.z));
        a[3] = __builtin_bit_cast(__bf16, f2bu(v0.w));
        a[4] = __builtin_bit_cast(__bf16, f2bu(v1.x));
        a[5] = __builtin_bit_cast(__bf16, f2bu(v1.y));
        a[6] = __builtin_bit_cast(__bf16, f2bu(v1.z));
        a[7] = __builtin_bit_cast(__bf16, f2bu(v1.w));
        const u16* Bb = kqvwT + it * 32 + q8;
#pragma unroll
        for (int j = 0; j < 3; ++j) {
            bf16x8 bb = *(const bf16x8*)(Bb + (size_t)(wn + j * 16 + l15) * 512);
            acc[j] = __builtin_amdgcn_mfma_f32_16x16x32_bf16(a, bb, acc[j], 0, 0, 0);
        }
    }

    // ---- epilogue: k -> kb, q -> qb, v -> Ts transpose -> vT ----
    __syncthreads();                            // phase-B readers done before T reuse
    u16* Ts = T;                                // [64][20] = 1280 els, aliases T
    int rq = q16 * 4;
#pragma unroll
    for (int rr = 0; rr < 4; ++rr) {
        int mloc = rq + rr;
        size_t mg = (size_t)(b * LL + l0 + mloc);
#pragma unroll
        for (int j = 0; j < 3; ++j) {
            int n = wn + j * 16 + l15;
            u16 hv = f2bu(acc[j][rr] + kqvb[n]);
            if (n < 64)       kb[mg * 64 + n] = hv;
            else if (n < 128) qb[mg * 64 + (n - 64)] = hv;
            else              Ts[(n - 128) * 20 + mloc] = hv;
        }
    }
    __syncthreads();
    int d = t >> 2, lo2 = (t & 3) * 4;
    *(ushort4*)(vT + ((size_t)(b * 64 + d)) * 512 + l0 + lo2) =
        *(const ushort4*)(Ts + d * 20 + lo2);
}

// ========== MFMA flash attention, split-K across 4 waves (unchanged) ==========
#define VLD 136
__global__ __launch_bounds__(256, 4)
void attn_kernel(const u16* __restrict__ qb, const u16* __restrict__ kb,
                 const u16* __restrict__ vT, u16* __restrict__ head) {
    __shared__ u16 Ps[4 * 16 * VLD];
    __shared__ float Osh[4][16 * 65];
    __shared__ float Msh[4][16], Lsh[4][16];
    int b = blockIdx.y, q0 = blockIdx.x * 16;
    int t = threadIdx.x, lane = t & 63, w = t >> 6;
    int l15 = lane & 15, q16 = lane >> 4, q8 = q16 * 8;
    int kc = w * 128;
    const u16* qg = qb + (size_t)b * LL * DA;
    const u16* kg = kb + (size_t)b * LL * DA;
    const u16* vg = vT + (size_t)b * DA * LL;

    bf16x8 aq[2];
#pragma unroll
    for (int s = 0; s < 2; ++s)
        aq[s] = *(const bf16x8*)(qg + (size_t)(q0 + l15) * DA + s * 32 + q8);

    f32x4 sc[8] = {};
#pragma unroll
    for (int j = 0; j < 8; ++j) {
#pragma unroll
        for (int s = 0; s < 2; ++s) {
            bf16x8 bk = *(const bf16x8*)(kg + (size_t)(kc + j * 16 + l15) * DA + s * 32 + q8);
            sc[j] = __builtin_amdgcn_mfma_f32_16x16x32_bf16(aq[s], bk, sc[j], 0, 0, 0);
        }
    }
    float mx[4], sm[4];
#pragma unroll
    for (int j = 0; j < 8; ++j)
#pragma unroll
        for (int rr = 0; rr < 4; ++rr) sc[j][rr] *= 0.125f;
#pragma unroll
    for (int rr = 0; rr < 4; ++rr) {
        float m0 = sc[0][rr];
#pragma unroll
        for (int j = 1; j < 8; ++j) m0 = fmaxf(m0, sc[j][rr]);
        m0 = fmaxf(m0, __shfl_xor(m0, 1));
        m0 = fmaxf(m0, __shfl_xor(m0, 2));
        m0 = fmaxf(m0, __shfl_xor(m0, 4));
        m0 = fmaxf(m0, __shfl_xor(m0, 8));
        mx[rr] = m0;
    }
#pragma unroll
    for (int j = 0; j < 8; ++j)
#pragma unroll
        for (int rr = 0; rr < 4; ++rr) sc[j][rr] = __expf(sc[j][rr] - mx[rr]);
#pragma unroll
    for (int rr = 0; rr < 4; ++rr) {
        float s0 = sc[0][rr];
#pragma unroll
        for (int j = 1; j < 8; ++j) s0 += sc[j][rr];
        s0 += __shfl_xor(s0, 1);
        s0 += __shfl_xor(s0, 2);
        s0 += __shfl_xor(s0, 4);
        s0 += __shfl_xor(s0, 8);
        sm[rr] = s0;
    }
    u16* Pw = Ps + w * 16 * VLD;
#pragma unroll
    for (int j = 0; j < 8; ++j)
#pragma unroll
        for (int rr = 0; rr < 4; ++rr)
            Pw[(q16 * 4 + rr) * VLD + j * 16 + l15] = f2bu(sc[j][rr]);
    f32x4 o[4] = {};
#pragma unroll
    for (int kt = 0; kt < 4; ++kt) {
        bf16x8 ap = *(const bf16x8*)(Pw + l15 * VLD + kt * 32 + q8);
#pragma unroll
        for (int j = 0; j < 4; ++j) {
            bf16x8 bv = *(const bf16x8*)(vg + (size_t)(j * 16 + l15) * LL + kc + kt * 32 + q8);
            o[j] = __builtin_amdgcn_mfma_f32_16x16x32_bf16(ap, bv, o[j], 0, 0, 0);
        }
    }
#pragma unroll
    for (int j = 0; j < 4; ++j)
#pragma unroll
        for (int rr = 0; rr < 4; ++rr)
            Osh[w][(q16 * 4 + rr) * 65 + j * 16 + l15] = o[j][rr];
    if (l15 == 0) {
#pragma unroll
        for (int rr = 0; rr < 4; ++rr) {
            Msh[w][q16 * 4 + rr] = mx[rr];
            Lsh[w][q16 * 4 + rr] = sm[rr];
        }
    }
    __syncthreads();
    int qq = t >> 4, dg = (t & 15) * 4;
    float m0 = Msh[0][qq], m1 = Msh[1][qq], m2 = Msh[2][qq], m3 = Msh[3][qq];
    float ms = fmaxf(fmaxf(m0, m1), fmaxf(m2, m3));
    float f0 = __expf(m0 - ms), f1 = __expf(m1 - ms), f2 = __expf(m2 - ms), f3 = __expf(m3 - ms);
    float lst = Lsh[0][qq] * f0 + Lsh[1][qq] * f1 + Lsh[2][qq] * f2 + Lsh[3][qq] * f3;
    float inv = 1.0f / lst;
    ushort4 res;
    u16* rp = (u16*)&res;
#pragma unroll
    for (int i = 0; i < 4; ++i) {
        int idx = qq * 65 + dg + i;
        float a = Osh[0][idx] * f0 + Osh[1][idx] * f1 + Osh[2][idx] * f2 + Osh[3][idx] * f3;
        rp[i] = f2bu(a * inv);
    }
    *(ushort4*)(head + (size_t)(b * LL + q0 + qq) * DA + dg) = res;
}

// ========== fused Toeplitz GEMM + proj + bias + gate, double-buffered pipeline ==========
__device__ __forceinline__ void mfma_tile64(const u16* As, const u16* Bs,
                                            f32x4 acc[4][4], int wm, int wn,
                                            int l15, int q16) {
    int s7 = l15 & 7;
#pragma unroll
    for (int kk = 0; kk < 2; ++kk) {
        int j0 = kk * 4 + q16;
        bf16x8 a[4], bv[4];
#pragma unroll
        for (int i = 0; i < 4; ++i) {
            int row = wm + i * 16 + l15;
            a[i] = *(const bf16x8*)(As + (row * 8 + (j0 ^ s7)) * 8);
        }
#pragma unroll
        for (int j = 0; j < 4; ++j) {
            int row = wn + j * 16 + l15;
            bv[j] = *(const bf16x8*)(Bs + (row * 8 + (j0 ^ s7)) * 8);
        }
#pragma unroll
        for (int i = 0; i < 4; ++i)
#pragma unroll
            for (int j = 0; j < 4; ++j)
                acc[i][j] = __builtin_amdgcn_mfma_f32_16x16x32_bf16(a[i], bv[j], acc[i][j], 0, 0, 0);
    }
}

__device__ __forceinline__ void stage_pair(const u16* A, const u16* B, int ldk,
                                           int koff, u16* Ad, u16* Bd, int t) {
#pragma unroll
    for (int s = 0; s < 4; ++s) {
        int ci = t + s * 256;
        int grow = ci >> 3, gcol = ((ci & 7) ^ (grow & 7)) << 3;
        async_cp16(A + (size_t)grow * ldk + koff + gcol, Ad + ci * 8);
        async_cp16(B + (size_t)grow * ldk + koff + gcol, Bd + ci * 8);
    }
}

__global__ __launch_bounds__(256, 2)
void mix_kernel(const u16* __restrict__ wt,      // [512 m][512 l]
                const u16* __restrict__ vnT,     // [B][512 c][512 l]
                const u16* __restrict__ headb,   // [B][512 m][64 d]
                const u16* __restrict__ projwT,  // [512 c][64 d]
                const float* __restrict__ x,
                const float* __restrict__ tbias,
                const float* __restrict__ projb,
                float* __restrict__ out) {
    __shared__ u16 As[2][128 * 64];              // 2 x 16 KiB
    __shared__ u16 Bs[2][128 * 64];              // 2 x 16 KiB  (total 64 KiB, 2 blk/CU)
    int lid = blockIdx.x;
    int p8 = lid & 7, rest = lid >> 3;
    int mi = rest & 3, pair = (rest >> 2) * 8 + p8;   // pair in [0,128)
    int b = pair >> 2, m0 = mi * 128, c0 = (pair & 3) * 128;
    int t = threadIdx.x, lane = t & 63, wid = t >> 6;
    int wm = (wid >> 1) * 64, wn = (wid & 1) * 64;
    int l15 = lane & 15, q16 = lane >> 4;
    f32x4 acc[4][4] = {};
    const u16* Ag = wt + (size_t)m0 * 512;
    const u16* Bg = vnT + ((size_t)b * H2 + c0) * 512;
    const u16* Hg = headb + ((size_t)b * LL + m0) * DA;
    const u16* Pg = projwT + (size_t)c0 * DA;

    // prologue: stage tile 0 (Toeplitz k0=0) into buf 0
    stage_pair(Ag, Bg, 512, 0, As[0], Bs[0], t);
    __syncthreads();                             // drains DMA

    // 9-tile pipeline: 8 Toeplitz K-slabs + proj as tile 8; stage-next ∥ MFMA-current
    for (int it = 0; it < 9; ++it) {
        int nx = it + 1;
        if (nx < 8)
            stage_pair(Ag, Bg, 512, nx * 64, As[nx & 1], Bs[nx & 1], t);
        else if (nx == 8)
            stage_pair(Hg, Pg, 64, 0, As[0], Bs[0], t);
        mfma_tile64(As[it & 1], Bs[it & 1], acc, wm, wn, l15, q16);
        __syncthreads();                         // next-buf ready; cur buf released
    }

    int rq = q16 * 4;
#pragma unroll
    for (int i = 0; i < 4; ++i) {
#pragma unroll
        for (int rr = 0; rr < 4; ++rr) {
            int m = m0 + wm + i * 16 + rq + rr;
            float tb = tbias[m];
            const float* xrow = x + ((size_t)b * LL + m) * HH;
            float* orow = out + ((size_t)b * LL + m) * H2;
#pragma unroll
            for (int j = 0; j < 4; ++j) {
                int c = c0 + wn + j * 16 + l15;
                float val = acc[i][j][rr] + tb + projb[c];
                orow[c] = xrow[c] * val;
            }
        }
    }
}

extern "C" void kernel_launch(void* const* d_in, const int* in_sizes, int n_in,
                              void* d_out, int out_size, void* d_ws, size_t ws_size,
                              hipStream_t stream) {
    (void)in_sizes; (void)n_in; (void)out_size; (void)ws_size;
    const float* x     = (const float*)d_in[0];
    const float* gamma = (const float*)d_in[1];
    const float* beta  = (const float*)d_in[2];
    const float* wv    = (const float*)d_in[3];
    const float* tb    = (const float*)d_in[4];
    const float* kqvw  = (const float*)d_in[5];
    const float* kqvb  = (const float*)d_in[6];
    const float* projw = (const float*)d_in[7];
    const float* projb = (const float*)d_in[8];
    float* out = (float*)d_out;

    u16* vnT_bf  = (u16*)d_ws;                          // 16 MB
    u16* qb      = vnT_bf + (size_t)NB * LL * H2;       // 2 MB
    u16* kb      = qb + (size_t)NB * LL * DA;           // 2 MB
    u16* vTb     = kb + (size_t)NB * LL * DA;           // 2 MB
    u16* head_bf = vTb + (size_t)NB * LL * DA;          // 2 MB
    u16* wt_bf   = head_bf + (size_t)NB * LL * DA;      // 512 KB
    u16* kqvwT   = wt_bf + 512 * 512;                   // 192 KB
    u16* projwT  = kqvwT + 192 * 512;                   // 64 KB
    float2* stats = (float2*)(projwT + 64 * 512);       // 128 KB (8B-aligned)

    prep_kernel <<<5632, 256, 0, stream>>>(wv, kqvw, projw, x, wt_bf, kqvwT,
                                           projwT, stats);
    front_kernel<<<1024, 256, 0, stream>>>(x, gamma, beta, stats, kqvwT, kqvb,
                                           vnT_bf, qb, kb, vTb);
    attn_kernel <<<dim3(32, NB), 256, 0, stream>>>(qb, kb, vTb, head_bf);
    mix_kernel  <<<512, 256, 0, stream>>>(wt_bf, vnT_bf, head_bf, projwT,
                                          x, tb, projb, out);
}